// Round 2
// baseline (443.725 us; speedup 1.0000x reference)
//
#include <hip/hip_runtime.h>
#include <hip/hip_bf16.h>

typedef float f32x4 __attribute__((ext_vector_type(4)));
typedef short bf16x8 __attribute__((ext_vector_type(8)));

#define DIM 1024
#define NH 64          // HIDDEN
#define NB 64          // NUM_BASIS
#define M_TOTAL 65536  // B*T

// ws layout (bytes):
//   [0, 131072)          : in_w as bf16 [64][1024]
//   [131072, 147456)     : cT    [k][h] f32 (4096)
//   [147456, 163840)     : coefT [k][h] f32 (4096)  = -log2(e)/width^2
//   [163840, 180224)     : owT   [k][h] f32 (4096)

__device__ __forceinline__ unsigned cvt_pk_bf16(float a, float b) {
    unsigned r;
    asm("v_cvt_pk_bf16_f32 %0, %1, %2" : "=v"(r) : "v"(a), "v"(b));
    return r;  // low16 = bf16(a), high16 = bf16(b), RNE
}

__global__ void rbf_prep(const float* __restrict__ in_w,
                         const float* __restrict__ centers,
                         const float* __restrict__ log_widths,
                         const float* __restrict__ out_weight,
                         unsigned* __restrict__ wbf,
                         float* __restrict__ cT,
                         float* __restrict__ coefT,
                         float* __restrict__ owT) {
    const int tid = blockIdx.x * blockDim.x + threadIdx.x;
    const int nthr = gridDim.x * blockDim.x;
    // in_w fp32 -> bf16 (pairs along rows; DIM even so pairs never cross rows)
    for (int i = tid; i < (NH * DIM) / 2; i += nthr) {
        wbf[i] = cvt_pk_bf16(in_w[2 * i], in_w[2 * i + 1]);
    }
    // transposed tables [k][h]
    for (int i = tid; i < NH * NB; i += nthr) {
        const int k = i >> 6, h = i & 63;
        const float lw = log_widths[h * NB + k];
        const float w = log1pf(expf(lw)) + 0.001f;  // softplus + eps
        cT[i] = centers[h * NB + k];
        coefT[i] = -1.4426950408889634f / (w * w);
        owT[i] = out_weight[h * NB + k];
    }
}

__global__ __launch_bounds__(256, 3) void rbf_main(
    const float* __restrict__ x,
    const float* __restrict__ in_b,
    const float* __restrict__ out_bias,
    const unsigned* __restrict__ wbf,
    const float* __restrict__ cT,
    const float* __restrict__ coefT,
    const float* __restrict__ owT,
    float* __restrict__ out) {
    __shared__ float s_c[NH * NB];
    __shared__ float s_cf[NH * NB];
    __shared__ float s_ow[NH * NB];

    const int t = threadIdx.x;
    // stage tables into LDS (vectorized straight copy; already transposed)
    for (int i = t; i < (NH * NB) / 4; i += 256) {
        ((float4*)s_c)[i] = ((const float4*)cT)[i];
        ((float4*)s_cf)[i] = ((const float4*)coefT)[i];
        ((float4*)s_ow)[i] = ((const float4*)owT)[i];
    }
    __syncthreads();

    const int lane = t & 63;
    const int wave = t >> 6;
    const int l15 = lane & 15;   // row-within-tile (A) / col (B,D)
    const int lk = lane >> 4;    // k-group 0..3
    const long rowbase = (long)blockIdx.x * 128 + wave * 32;

    // ---- GEMM: z[32 rows][64 h] via mfma_f32_16x16x32_bf16 ----
    f32x4 acc[2][4];
#pragma unroll
    for (int m = 0; m < 2; ++m)
#pragma unroll
        for (int n = 0; n < 4; ++n) acc[m][n] = (f32x4)0.0f;

    const float* xa0 = x + (rowbase + l15) * DIM + lk * 8;
    const float* xa1 = xa0 + 16 * DIM;
    const short* wb = (const short*)wbf;  // bf16 [64][1024]
    const short* wbp0 = wb + (0 * 16 + l15) * DIM + lk * 8;
    const short* wbp1 = wb + (1 * 16 + l15) * DIM + lk * 8;
    const short* wbp2 = wb + (2 * 16 + l15) * DIM + lk * 8;
    const short* wbp3 = wb + (3 * 16 + l15) * DIM + lk * 8;

#pragma unroll 2
    for (int ks = 0; ks < DIM / 32; ++ks) {
        const int k0 = ks * 32;
        bf16x8 bf[4];
        bf[0] = *(const bf16x8*)(wbp0 + k0);
        bf[1] = *(const bf16x8*)(wbp1 + k0);
        bf[2] = *(const bf16x8*)(wbp2 + k0);
        bf[3] = *(const bf16x8*)(wbp3 + k0);
        const float* xs[2] = {xa0 + k0, xa1 + k0};
#pragma unroll
        for (int m = 0; m < 2; ++m) {
            const float4 lo = *(const float4*)(xs[m]);
            const float4 hi = *(const float4*)(xs[m] + 4);
            union { unsigned u[4]; bf16x8 v; } af;
            af.u[0] = cvt_pk_bf16(lo.x, lo.y);
            af.u[1] = cvt_pk_bf16(lo.z, lo.w);
            af.u[2] = cvt_pk_bf16(hi.x, hi.y);
            af.u[3] = cvt_pk_bf16(hi.z, hi.w);
#pragma unroll
            for (int n = 0; n < 4; ++n)
                acc[m][n] = __builtin_amdgcn_mfma_f32_16x16x32_bf16(
                    af.v, bf[n], acc[m][n], 0, 0, 0);
        }
    }

    // ---- RBF + reduction ----
    float zb[4];
#pragma unroll
    for (int n = 0; n < 4; ++n) zb[n] = in_b[n * 16 + l15];
    const float ob = out_bias[0];

    float part[8];
#pragma unroll
    for (int i = 0; i < 8; ++i) part[i] = 0.0f;

#pragma unroll
    for (int n = 0; n < 4; ++n) {
        const int hb = n * 16 + l15;
        float z[8];
#pragma unroll
        for (int m = 0; m < 2; ++m)
#pragma unroll
            for (int r = 0; r < 4; ++r) z[m * 4 + r] = acc[m][n][r] + zb[n];
#pragma unroll 4
        for (int k = 0; k < NB; ++k) {
            const float c = s_c[k * 64 + hb];
            const float cf = s_cf[k * 64 + hb];
            const float w8 = s_ow[k * 64 + hb];
#pragma unroll
            for (int i = 0; i < 8; ++i) {
                const float tt = z[i] - c;
                part[i] = fmaf(__builtin_amdgcn_exp2f(tt * tt * cf), w8, part[i]);
            }
        }
    }

    // reduce across the 16 lanes sharing a row-group (xor within 16-lane groups)
#pragma unroll
    for (int off = 1; off < 16; off <<= 1)
#pragma unroll
        for (int i = 0; i < 8; ++i) part[i] += __shfl_xor(part[i], off);

    if (l15 == 0) {
#pragma unroll
        for (int m = 0; m < 2; ++m)
#pragma unroll
            for (int r = 0; r < 4; ++r)
                out[rowbase + m * 16 + lk * 4 + r] = part[m * 4 + r] + ob;
    }
}

extern "C" void kernel_launch(void* const* d_in, const int* in_sizes, int n_in,
                              void* d_out, int out_size, void* d_ws, size_t ws_size,
                              hipStream_t stream) {
    const float* x = (const float*)d_in[0];
    const float* in_w = (const float*)d_in[1];
    const float* in_b = (const float*)d_in[2];
    const float* centers = (const float*)d_in[3];
    const float* log_widths = (const float*)d_in[4];
    const float* out_weight = (const float*)d_in[5];
    const float* out_bias = (const float*)d_in[6];
    float* out = (float*)d_out;

    unsigned* wbf = (unsigned*)d_ws;
    float* cT = (float*)((char*)d_ws + 131072);
    float* coefT = cT + NH * NB;
    float* owT = coefT + NH * NB;

    rbf_prep<<<64, 256, 0, stream>>>(in_w, centers, log_widths, out_weight,
                                     wbf, cT, coefT, owT);
    rbf_main<<<M_TOTAL / 128, 256, 0, stream>>>(x, in_b, out_bias, wbf, cT,
                                                coefT, owT, out);
}